// Round 4
// 192.451 us; speedup vs baseline: 1.0215x; 1.0215x over previous
//
#include <hip/hip_runtime.h>

// Problem constants (from reference): B=64 batches, grid 64^3, P=4096 points.
#define BB 64
#define NDIM 64
#define GRID3 (NDIM * NDIM * NDIM)   // 262144 bins per batch
#define NPTS 4096

// clang native vector types for __builtin_nontemporal_* (HIP_vector_type
// structs are rejected by the builtin; these are layout-identical).
typedef float v4f __attribute__((ext_vector_type(4)));

// d_ws layout: [0,16KB) u32 slab counters (BB*64), [16KB, 16KB+32MB) u16 lists
// (4096 slots per (b,slab) — worst case all points of a batch in one slab).
//
// NOTE on the measured 196 us: rocprof shows the timed window contains
// ~2x 512 MiB fillBufferAligned poison fills (~80 us each) — a ~160 us
// harness floor. Our three dispatches are the remaining ~36 us; this
// revision targets that slice (NT stores/loads + vectorized binning).

// Kernel 1: visit each point ONCE (4 points/thread via 3x float4 = 48 B/lane,
// fully coalesced), compact into per-(b,slab) u16 lists.
__global__ __launch_bounds__(256) void bin_kernel(const float* __restrict__ z,
                                                  unsigned int* __restrict__ cnt,
                                                  unsigned short* __restrict__ list) {
    int t = blockIdx.x * 256 + threadIdx.x;   // 0 .. BB*NPTS/4 - 1
    const v4f* zp = (const v4f*)z + (size_t)t * 3;
    v4f v0 = __builtin_nontemporal_load(zp + 0);
    v4f v1 = __builtin_nontemporal_load(zp + 1);
    v4f v2 = __builtin_nontemporal_load(zp + 2);
    const int b = t >> 10;                    // 4096/4 = 1024 threads per batch

    float px[4] = {v0.x, v0.w, v1.z, v2.y};
    float py[4] = {v0.y, v1.x, v1.w, v2.z};
    float pz[4] = {v0.z, v1.y, v2.x, v2.w};

    #pragma unroll
    for (int k = 0; k < 4; ++k) {
        int i0 = min(max((int)floorf(px[k] * 64.0f), 0), 63);
        int i1 = min(max((int)floorf(py[k] * 64.0f), 0), 63);
        int i2 = min(max((int)floorf(pz[k] * 64.0f), 0), 63);
        int sb = (b << 6) | i0;
        unsigned int slot = atomicAdd(&cnt[sb], 1u);
        // stays in normal cache path: re-read by fused_kernel right after
        list[((size_t)sb << 12) | slot] = (unsigned short)((i1 << 6) | i2);
    }
}

// Kernel 2: one block per (batch b, slab i0). LDS histogram from the compact
// list (~64 points), segmented register suffix-scan, float4 output pass.
__global__ __launch_bounds__(256) void fused_kernel(const float* __restrict__ x,
                                                    const unsigned int* __restrict__ cnt,
                                                    const unsigned short* __restrict__ list,
                                                    float* __restrict__ counts,
                                                    float* __restrict__ rm) {
    __shared__ unsigned int H[NDIM * NDIM];   // 16 KB (i1,i2) histogram

    const int slab = blockIdx.x;   // i0
    const int b    = blockIdx.y;
    const int tid  = threadIdx.x;
    const int sb   = (b << 6) | slab;

    // 1. zero LDS histogram (uint4)
    uint4* H4 = (uint4*)H;
    #pragma unroll
    for (int i = 0; i < 4; ++i) H4[tid + i * 256] = make_uint4(0u, 0u, 0u, 0u);
    __syncthreads();

    // 2. histogram this slab's compact point list (mean ~64 entries)
    const int n = (int)cnt[sb];
    const unsigned short* lp = list + ((size_t)sb << 12);
    for (int p = tid; p < n; p += 256)
        atomicAdd(&H[lp[p]], 1u);
    __syncthreads();

    // 3. segmented suffix scan: thread owns a quarter-row (16 bins, 4x b128),
    //    register prefix, 2-step shfl across the 4-lane segment group.
    {
        const int row = tid >> 2;
        const int seg = tid & 3;
        const int q4  = (row << 4) + (seg << 2);

        float e[16], pr[16];
        #pragma unroll
        for (int i = 0; i < 4; ++i) {
            uint4 q = H4[q4 + i];
            e[4*i+0] = (float)q.x; e[4*i+1] = (float)q.y;
            e[4*i+2] = (float)q.z; e[4*i+3] = (float)q.w;
        }
        float p = 0.0f;
        #pragma unroll
        for (int j = 0; j < 16; ++j) { p += e[j]; pr[j] = p; }
        const float seg_sum = p;

        float sc = seg_sum;
        float n1 = __shfl_up(sc, 1, 4); if (seg >= 1) sc += n1;
        float n2 = __shfl_up(sc, 2, 4); if (seg >= 2) sc += n2;
        const float T       = __shfl(sc, 3, 4);   // row total
        const float segExcl = sc - seg_sum;

        float4* Hf4 = (float4*)H;
        #pragma unroll
        for (int i = 0; i < 4; ++i) {
            float4 w;
            w.x = e[4*i+0] + T - (segExcl + pr[4*i+0]);
            w.y = e[4*i+1] + T - (segExcl + pr[4*i+1]);
            w.z = e[4*i+2] + T - (segExcl + pr[4*i+2]);
            w.w = e[4*i+3] + T - (segExcl + pr[4*i+3]);
            Hf4[q4 + i] = w;
        }
    }
    __syncthreads();

    // 4. float4 output pass: 16 B/lane lane-contiguous NT stores (write-once
    //    data, evict-first). s non-increasing within a row and each float4
    //    sits inside one row, so s.x>0 predicates the quad. x read is a
    //    contiguous prefix of each 256 B row -> line-efficient.
    const v4f* Hs = (const v4f*)H;
    const v4f* x4 = (const v4f*)x;
    v4f* c4 = (v4f*)counts;
    v4f* r4 = (v4f*)rm;
    const size_t base4 = ((size_t)b << 16) + ((size_t)slab << 10);   // float4 units

    #pragma unroll
    for (int i = 0; i < 4; ++i) {
        int j = tid + i * 256;            // 0..1023
        v4f s = Hs[j];
        size_t idx = base4 + j;
        __builtin_nontemporal_store(s, &c4[idx]);
        v4f xv = (v4f)(0.0f);
        if (s.x > 0.0f) xv = __builtin_nontemporal_load(&x4[idx]);
        v4f r;
        r.x = (s.x > 0.0f) ? xv.x : 0.0f;
        r.y = (s.y > 0.0f) ? xv.y : 0.0f;
        r.z = (s.z > 0.0f) ? xv.z : 0.0f;
        r.w = (s.w > 0.0f) ? xv.w : 0.0f;
        __builtin_nontemporal_store(r, &r4[idx]);
    }
}

extern "C" void kernel_launch(void* const* d_in, const int* in_sizes, int n_in,
                              void* d_out, int out_size, void* d_ws, size_t ws_size,
                              hipStream_t stream) {
    const float* x = (const float*)d_in[0];   // [BB, 64,64,64]
    const float* z = (const float*)d_in[1];   // [BB, NPTS, 3]

    float* counts = (float*)d_out;                        // output 0
    float* rm     = counts + (size_t)BB * GRID3;          // output 1

    unsigned int*   cnt  = (unsigned int*)d_ws;                       // 16 KB
    unsigned short* list = (unsigned short*)((char*)d_ws + 16384);    // 32 MB

    // zero the slab counters (ws is poisoned 0xAA before every timed call)
    (void)hipMemsetAsync(cnt, 0, BB * 64 * sizeof(unsigned int), stream);

    bin_kernel<<<(BB * NPTS / 4) / 256, 256, 0, stream>>>(z, cnt, list);

    dim3 grid(NDIM, BB);   // x = slab (i0), y = batch
    fused_kernel<<<grid, 256, 0, stream>>>(x, cnt, list, counts, rm);
}